// Round 12
// baseline (55.606 us; speedup 1.0000x reference)
//
#include <hip/hip_runtime.h>
#include <math.h>

typedef __attribute__((ext_vector_type(8))) short short8;
typedef __attribute__((ext_vector_type(4))) float f32x4;

#define DT_STEP 0.1f

static __device__ __forceinline__ unsigned bf16rne(float f) {
    unsigned u = __builtin_bit_cast(unsigned, f);
    return (u + 0x7fffu + ((u >> 16) & 1u)) >> 16;
}
static __device__ __forceinline__ unsigned bf16pk2(float lo, float hi) {
    unsigned r;
    asm("v_cvt_pk_bf16_f32 %0, %1, %2" : "=v"(r) : "v"(lo), "v"(hi));
    return r;
}
static __device__ __forceinline__ float tanh_fast(float v) {
    float e = __expf(2.0f * v);
    return 1.0f - 2.0f / (e + 1.0f);
}

// HW transpose read (verified r9/r10). RACE LESSON (r11): tr reads can bypass
// pending same-wave ds_writes -> ALWAYS put a runtime lgkmcnt(0) drain between
// producer stores and these reads (compile-time sched_barrier is NOT enough),
// and another before consuming the results.
static __device__ __forceinline__ uint4 tr_read8(unsigned a) {
    uint2 lo, hi;
    asm volatile("ds_read_b64_tr_b16 %0, %2 offset:0\n\t"
                 "ds_read_b64_tr_b16 %1, %2 offset:128"
                 : "=&v"(lo), "=&v"(hi) : "v"(a));
    return make_uint4(lo.x, lo.y, hi.x, hi.y);
}

static __device__ __forceinline__ void mm3(const float* A, const float* B, float* C) {
#pragma unroll
    for (int i = 0; i < 3; ++i)
#pragma unroll
        for (int j = 0; j < 3; ++j)
            C[i * 3 + j] = A[i * 3 + 0] * B[0 * 3 + j] + A[i * 3 + 1] * B[1 * 3 + j] + A[i * 3 + 2] * B[2 * 3 + j];
}
static __device__ __forceinline__ void mv3(const float* A, const float* x, float* y) {
#pragma unroll
    for (int i = 0; i < 3; ++i) y[i] = A[i * 3 + 0] * x[0] + A[i * 3 + 1] * x[1] + A[i * 3 + 2] * x[2];
}
static __device__ __forceinline__ void mtv3(const float* A, const float* x, float* y) {
#pragma unroll
    for (int i = 0; i < 3; ++i) y[i] = A[0 * 3 + i] * x[0] + A[1 * 3 + i] * x[1] + A[2 * 3 + i] * x[2];
}
static __device__ __forceinline__ void cross3(const float* p, const float* u, float* y) {
    y[0] = p[1] * u[2] - p[2] * u[1];
    y[1] = p[2] * u[0] - p[0] * u[2];
    y[2] = p[0] * u[1] - p[1] * u[0];
}

// ws layout (unsigned short elements) — verified r6/r7/r9/r10:
//  [0,4096)      W1A: [n1=128][k=32] bf16, k>=12 zero
//  [4096,20480)  W2B: [n2=128][k=128] bf16
//  [20480,22528) W3B: [(kt*4+lg)*16 + n3pad]*8, n3pad<6 valid else 0
__global__ __launch_bounds__(256)
void weights_prep(const float* __restrict__ W1, const float* __restrict__ W2,
                  const float* __restrict__ W3, unsigned short* __restrict__ ws) {
    int i = blockIdx.x * 256 + threadIdx.x;
    if (i < 4096) {
        int n = i >> 5, k = i & 31;
        ws[i] = (k < 12) ? (unsigned short)bf16rne(W1[n * 12 + k]) : (unsigned short)0;
    } else if (i < 20480) {
        ws[i] = (unsigned short)bf16rne(W2[i - 4096]);
    } else if (i < 22528) {
        int j = i - 20480;
        int jj = j & 7;
        int l = (j >> 3) & 15;     // n3 (valid < 6)
        int kl = j >> 7;           // kt*4+lg
        int k = kl * 8 + jj;
        ws[i] = (l < 6) ? (unsigned short)bf16rne(W3[l * 128 + k]) : (unsigned short)0;
    }
}

// r10 structure + drain set (verified stable), plus:
//  - P0: coalesced float4 staging of s/a/h0 into l12 (free during P1);
//    per-element fields then read from LDS (kills ~36 uncoalesced scalar
//    HBM loads per lane).
//  - SE3 reuses xv for R/v; p staged -> no second s read.
//  - h1t moved to offset 9216 (clear of staging regions).
// LDS regions: stage s[0,4608) a[4608,6144) h0[6144,9216); h1t[9216,11264);
// l12 T-layout tile = full [0,16384) from P2 on; dvt overlay [0,2048) at end.
__global__ __launch_bounds__(64, 3)
void auv_mfma9_kernel(const float* __restrict__ s, const float* __restrict__ a,
                      const float* __restrict__ h0, const float* __restrict__ W_ih,
                      const float* __restrict__ W_hh, const unsigned short* __restrict__ Wbf,
                      float* __restrict__ out, int K)
{
    __shared__ __align__(16) char lds[16384];
    const int lane = threadIdx.x & 63;
    const int l15  = lane & 15;
    const int lg   = lane >> 4;

    char* l12 = &lds[0];
    char* h1t = &lds[9216];
    char* dvt = &lds[0];

    const unsigned trb   = (unsigned)(lg * 256 + l15 * 8);
    const unsigned stoff = ((l15 >> 2) << 7) + ((l15 & 3) << 5) + (lg << 3);

    const unsigned short* W1A = Wbf;
    const unsigned short* W2B = Wbf + 4096;
    const unsigned short* W3B = Wbf + 20480;

    const int e0    = blockIdx.x * 64;
    const int e_raw = e0 + lane;
    const int e  = e_raw < K ? e_raw : K - 1;
    const bool live = e_raw < K;
    const bool full = (e0 + 64 <= K);

    // ---------------- Phase 0/1: inputs (coalesced staging) + RNN ----------------
    float xv[21], h0v[12], pv3[3];
    if (full) {
        const float4* sg = (const float4*)(s + (size_t)e0 * 18);   // 288 f4
        float4* st = (float4*)(lds + 0);
#pragma unroll
        for (int i = 0; i < 4; ++i) st[i * 64 + lane] = sg[i * 64 + lane];
        if (lane < 32) st[256 + lane] = sg[256 + lane];
        const float4* ag = (const float4*)(a + (size_t)e0 * 6);    // 96 f4
        float4* at = (float4*)(lds + 4608);
        at[lane] = ag[lane];
        if (lane < 32) at[64 + lane] = ag[64 + lane];
        const float4* hg = (const float4*)(h0 + (size_t)e0 * 12);  // 192 f4
        float4* ht = (float4*)(lds + 6144);
#pragma unroll
        for (int i = 0; i < 3; ++i) ht[i * 64 + lane] = hg[i * 64 + lane];
        asm volatile("s_waitcnt vmcnt(0) lgkmcnt(0)" ::: "memory");   // staged data visible
        __builtin_amdgcn_sched_barrier(0);

        const float* sst = (const float*)(lds) + lane * 18;
        pv3[0] = sst[0]; pv3[1] = sst[1]; pv3[2] = sst[2];
#pragma unroll
        for (int i = 0; i < 15; ++i) xv[i] = sst[3 + i];
        const float* ast = (const float*)(lds + 4608) + lane * 6;
#pragma unroll
        for (int i = 0; i < 6; ++i) xv[15 + i] = ast[i];
        const float* hst = (const float*)(lds + 6144) + lane * 12;
#pragma unroll
        for (int i = 0; i < 12; ++i) h0v[i] = hst[i];
    } else {
        const float* srow = s  + (size_t)e * 18;
        const float* arow = a  + (size_t)e * 6;
        const float* hrow = h0 + (size_t)e * 12;
        pv3[0] = srow[0]; pv3[1] = srow[1]; pv3[2] = srow[2];
#pragma unroll
        for (int i = 0; i < 15; ++i) xv[i] = srow[3 + i];
#pragma unroll
        for (int i = 0; i < 6; ++i)  xv[15 + i] = arow[i];
#pragma unroll
        for (int i = 0; i < 12; ++i) h0v[i] = hrow[i];
    }

    float h1v[12];
#pragma unroll
    for (int j = 0; j < 12; ++j) {
        float acc = 0.f;
        const float* wih = W_ih + j * 21;
#pragma unroll
        for (int i = 0; i < 21; ++i) acc = fmaf(wih[i], xv[i], acc);
        const float* whh = W_hh + j * 12;
#pragma unroll
        for (int i = 0; i < 12; ++i) acc = fmaf(whh[i], h0v[i], acc);
        h1v[j] = tanh_fast(acc);
    }

    if (live) {
        float4* h4 = (float4*)(out + (size_t)K * 18 + (size_t)e * 12);
        h4[0] = make_float4(h1v[0], h1v[1], h1v[2], h1v[3]);
        h4[1] = make_float4(h1v[4], h1v[5], h1v[6], h1v[7]);
        h4[2] = make_float4(h1v[8], h1v[9], h1v[10], h1v[11]);
    }

    // T14: issue W2B nt=0 B-frag loads NOW (consumed in P4)
    short8 bfr[4];
#pragma unroll
    for (int kt = 0; kt < 4; ++kt)
        bfr[kt] = __builtin_bit_cast(short8,
            *(const uint4*)(W2B + (l15 * 128 + kt * 32 + lg * 8)));

    // h1 -> LDS: row=lane, 16 bf16 (12 valid + 4 zero); chunk swizzle by (row&1)
    {
        unsigned p0 = bf16pk2(h1v[0], h1v[1]);
        unsigned p1 = bf16pk2(h1v[2], h1v[3]);
        unsigned p2 = bf16pk2(h1v[4], h1v[5]);
        unsigned p3 = bf16pk2(h1v[6], h1v[7]);
        unsigned p4 = bf16pk2(h1v[8], h1v[9]);
        unsigned p5 = bf16pk2(h1v[10], h1v[11]);
        int rq = (lane & 1) << 4;
        *(uint4*)(h1t + lane * 32 + (0 ^ rq))  = make_uint4(p0, p1, p2, p3);
        *(uint4*)(h1t + lane * 32 + (16 ^ rq)) = make_uint4(p4, p5, 0u, 0u);
    }
    asm volatile("s_waitcnt lgkmcnt(0)" ::: "memory");
    __builtin_amdgcn_sched_barrier(0);

    const short8 zfrag = {0, 0, 0, 0, 0, 0, 0, 0};

    // ---------------- Phase 2: Layer 1 via MFMA (K=32 zero-padded) ----------------
    short8 af1[4];
#pragma unroll
    for (int rt = 0; rt < 4; ++rt) {
        af1[rt] = zfrag;
        if (lg < 2) {
            int row = rt * 16 + l15;
            af1[rt] = __builtin_bit_cast(short8,
                *(const uint4*)(h1t + row * 32 + ((lg * 16) ^ ((row & 1) << 4))));
        }
    }
    asm volatile("s_waitcnt lgkmcnt(0)" ::: "memory");   // af1 in regs before l12 overwrite
    __builtin_amdgcn_sched_barrier(0);

#pragma unroll 1
    for (int nt = 0; nt < 8; ++nt) {
        short8 b1 = __builtin_bit_cast(short8,
            *(const uint4*)(W1A + ((nt * 16 + l15) * 32 + lg * 8)));
#pragma unroll
        for (int rt = 0; rt < 4; ++rt) {
            f32x4 z = {0.f, 0.f, 0.f, 0.f};
            f32x4 c1 = __builtin_amdgcn_mfma_f32_16x16x32_bf16(af1[rt], b1, z, 0, 0, 0);
            float v0 = fmaxf(c1[0], 0.1f * c1[0]);
            float v1 = fmaxf(c1[1], 0.1f * c1[1]);
            float v2 = fmaxf(c1[2], 0.1f * c1[2]);
            float v3 = fmaxf(c1[3], 0.1f * c1[3]);
            *(uint2*)(l12 + rt * 4096 + nt * 512 + stoff) =
                make_uint2(bf16pk2(v0, v1), bf16pk2(v2, v3));
        }
    }
    asm volatile("s_waitcnt lgkmcnt(0)" ::: "memory");   // stores done before tr reads (r11 lesson)
    __builtin_amdgcn_sched_barrier(0);

    // ---------------- Phase 3: A2 fragments via tr reads ----------------
    short8 af2[4][4];
#pragma unroll
    for (int rt = 0; rt < 4; ++rt)
#pragma unroll
        for (int kt = 0; kt < 4; ++kt)
            af2[rt][kt] = __builtin_bit_cast(short8, tr_read8(trb + rt * 4096 + kt * 1024));
    asm volatile("s_waitcnt lgkmcnt(0)" ::: "memory");   // rule #18: before MFMA use
    __builtin_amdgcn_sched_barrier(0);

    // T14: W3B loads issued early (consumed in P6)
    short8 b3f[4];
#pragma unroll
    for (int kt = 0; kt < 4; ++kt)
        b3f[kt] = __builtin_bit_cast(short8,
            *(const uint4*)(W3B + (((kt * 4 + lg) * 16 + l15) * 8)));

    // ---------------- Phase 4: Layer 2 via MFMA (bfr preloaded; bnext prefetch) ----------------
#pragma unroll 1
    for (int nt = 0; nt < 8; ++nt) {
        short8 bnext[4];
        if (nt < 7) {
#pragma unroll
            for (int kt = 0; kt < 4; ++kt)
                bnext[kt] = __builtin_bit_cast(short8,
                    *(const uint4*)(W2B + (((nt + 1) * 16 + l15) * 128 + kt * 32 + lg * 8)));
        }
#pragma unroll
        for (int rt = 0; rt < 4; ++rt) {
            f32x4 c2 = {0.f, 0.f, 0.f, 0.f};
#pragma unroll
            for (int kt = 0; kt < 4; ++kt)
                c2 = __builtin_amdgcn_mfma_f32_16x16x32_bf16(af2[rt][kt], bfr[kt], c2, 0, 0, 0);
            float v0 = fmaxf(c2[0], 0.1f * c2[0]);
            float v1 = fmaxf(c2[1], 0.1f * c2[1]);
            float v2 = fmaxf(c2[2], 0.1f * c2[2]);
            float v3 = fmaxf(c2[3], 0.1f * c2[3]);
            *(uint2*)(l12 + rt * 4096 + nt * 512 + stoff) =
                make_uint2(bf16pk2(v0, v1), bf16pk2(v2, v3));
        }
#pragma unroll
        for (int kt = 0; kt < 4; ++kt) bfr[kt] = bnext[kt];
    }
    asm volatile("s_waitcnt lgkmcnt(0)" ::: "memory");   // stores done before tr reads (r11 lesson)
    __builtin_amdgcn_sched_barrier(0);

    // ---------------- Phase 5: A3 fragments via tr reads + SE3 part 1 ----------------
    short8 af3[4][4];
#pragma unroll
    for (int rt = 0; rt < 4; ++rt)
#pragma unroll
        for (int kt = 0; kt < 4; ++kt)
            af3[rt][kt] = __builtin_bit_cast(short8, tr_read8(trb + rt * 4096 + kt * 1024));

    // dv-independent SE(3) work under the tr-read latency; R/v from xv, p staged
    const float* v = &xv[9];
    const float* p = pv3;
    const float* R = &xv[0];

    float Rn[9], pn[3], pinv[3], Rvl[3], Rva[3], px[3];
    {
        float rho[3] = {v[0] * DT_STEP, v[1] * DT_STEP, v[2] * DT_STEP};
        float phi[3] = {v[3] * DT_STEP, v[4] * DT_STEP, v[5] * DT_STEP};
        float th2 = phi[0] * phi[0] + phi[1] * phi[1] + phi[2] * phi[2];

        float A, B, C;
        if (th2 < 1e-8f) {
            A = 1.0f - th2 * (1.0f / 6.0f);
            B = 0.5f - th2 * (1.0f / 24.0f);
            C = (1.0f / 6.0f) - th2 * (1.0f / 120.0f);
        } else {
            float th = sqrtf(th2);
            float sn = sinf(th), cs = cosf(th);
            A = sn / th;
            B = (1.0f - cs) / th2;
            C = (th - sn) / (th2 * th);
        }

        float S[9] = {0.f, -phi[2], phi[1], phi[2], 0.f, -phi[0], -phi[1], phi[0], 0.f};
        float S2[9];
        mm3(S, S, S2);

        float Re[9], V[9];
#pragma unroll
        for (int i = 0; i < 9; ++i) {
            float I = (i == 0 || i == 4 || i == 8) ? 1.0f : 0.0f;
            Re[i] = I + A * S[i] + B * S2[i];
            V[i]  = I + B * S[i] + C * S2[i];
        }

        float pe[3];
        mv3(V, rho, pe);
        mm3(R, Re, Rn);
        mv3(R, pe, pn);
        pn[0] += p[0]; pn[1] += p[1]; pn[2] += p[2];

        mtv3(Rn, pn, pinv);
        pinv[0] = -pinv[0]; pinv[1] = -pinv[1]; pinv[2] = -pinv[2];

        mv3(R, &v[0], Rvl);
        mv3(R, &v[3], Rva);
        cross3(p, Rva, px);
    }

    asm volatile("s_waitcnt lgkmcnt(0)" ::: "memory");   // af3 ready; l12 free for dvt
    __builtin_amdgcn_sched_barrier(0);

    // ---------------- Phase 6: Layer 3 via MFMA (n3 padded to 16) ----------------
    f32x4 c3[4];
#pragma unroll
    for (int rt = 0; rt < 4; ++rt) c3[rt] = (f32x4){0.f, 0.f, 0.f, 0.f};
#pragma unroll
    for (int kt = 0; kt < 4; ++kt) {
#pragma unroll
        for (int rt = 0; rt < 4; ++rt)
            c3[rt] = __builtin_amdgcn_mfma_f32_16x16x32_bf16(af3[rt][kt], b3f[kt], c3[rt], 0, 0, 0);
    }

    // ---------------- Phase 7: dv redistribute via dvt overlay (64 rows x 32B f32) ----------------
    float dvv[6];
    if (l15 < 6) {
#pragma unroll
        for (int rt = 0; rt < 4; ++rt)
#pragma unroll
            for (int r = 0; r < 4; ++r) {
                int row = rt * 16 + lg * 4 + r;
                *(float*)(dvt + row * 32 + l15 * 4) = c3[rt][r];
            }
    }
    asm volatile("s_waitcnt lgkmcnt(0)" ::: "memory");
    __builtin_amdgcn_sched_barrier(0);
    {
        const float* dr = (const float*)(dvt + lane * 32);
        dvv[0] = dr[0]; dvv[1] = dr[1]; dvv[2] = dr[2];
        dvv[3] = dr[3]; dvv[4] = dr[4]; dvv[5] = dr[5];
    }

    // ---------------- Phase 8: SE(3) tail (dv-dependent) ----------------
    float u6[6];
    u6[0] = Rvl[0] + px[0] + dvv[0];
    u6[1] = Rvl[1] + px[1] + dvv[1];
    u6[2] = Rvl[2] + px[2] + dvv[2];
    u6[3] = Rva[0] + dvv[3];
    u6[4] = Rva[1] + dvv[4];
    u6[5] = Rva[2] + dvv[5];

    float Rul[3], Rua[3];
    mtv3(Rn, &u6[0], Rul);
    mtv3(Rn, &u6[3], Rua);
    float pxu[3];
    cross3(pinv, Rua, pxu);
    float vn[6];
    vn[0] = Rul[0] + pxu[0];
    vn[1] = Rul[1] + pxu[1];
    vn[2] = Rul[2] + pxu[2];
    vn[3] = Rua[0];
    vn[4] = Rua[1];
    vn[5] = Rua[2];

    if (live) {
        float* s_next = out + (size_t)e * 18;
        s_next[0] = pn[0]; s_next[1] = pn[1]; s_next[2] = pn[2];
#pragma unroll
        for (int i = 0; i < 9; ++i) s_next[3 + i] = Rn[i];
#pragma unroll
        for (int i = 0; i < 6; ++i) s_next[12 + i] = vn[i];

        float* dvo = out + (size_t)K * 30 + (size_t)e * 6;
#pragma unroll
        for (int r = 0; r < 6; ++r) dvo[r] = dvv[r];
    }
}

extern "C" void kernel_launch(void* const* d_in, const int* in_sizes, int n_in,
                              void* d_out, int out_size, void* d_ws, size_t ws_size,
                              hipStream_t stream) {
    const float* s    = (const float*)d_in[0];
    const float* a    = (const float*)d_in[1];
    const float* h0   = (const float*)d_in[2];
    const float* W_ih = (const float*)d_in[3];
    const float* W_hh = (const float*)d_in[4];
    const float* W1   = (const float*)d_in[5];
    const float* W2   = (const float*)d_in[6];
    const float* W3   = (const float*)d_in[7];

    int K = in_sizes[0] / 18;
    unsigned short* ws = (unsigned short*)d_ws;

    weights_prep<<<(22528 + 255) / 256, 256, 0, stream>>>(W1, W2, W3, ws);

    int grid = (K + 63) / 64;
    auv_mfma9_kernel<<<grid, 64, 0, stream>>>(s, a, h0, W_ih, W_hh, ws,
                                              (float*)d_out, K);
}

// Round 13
// 52.515 us; speedup vs baseline: 1.0589x; 1.0589x over previous
//
#include <hip/hip_runtime.h>
#include <math.h>

typedef __attribute__((ext_vector_type(8))) short short8;
typedef __attribute__((ext_vector_type(4))) float f32x4;

#define DT_STEP 0.1f

static __device__ __forceinline__ unsigned bf16rne(float f) {
    unsigned u = __builtin_bit_cast(unsigned, f);
    return (u + 0x7fffu + ((u >> 16) & 1u)) >> 16;
}
static __device__ __forceinline__ unsigned short bf16pk1(float f) {
    unsigned r;
    asm("v_cvt_pk_bf16_f32 %0, %1, %1" : "=v"(r) : "v"(f));
    return (unsigned short)r;
}
static __device__ __forceinline__ unsigned bf16pk2(float lo, float hi) {
    unsigned r;
    asm("v_cvt_pk_bf16_f32 %0, %1, %2" : "=v"(r) : "v"(lo), "v"(hi));
    return r;
}
static __device__ __forceinline__ float tanh_fast(float v) {
    float e = __expf(2.0f * v);
    return 1.0f - 2.0f / (e + 1.0f);
}

static __device__ __forceinline__ void mm3(const float* A, const float* B, float* C) {
#pragma unroll
    for (int i = 0; i < 3; ++i)
#pragma unroll
        for (int j = 0; j < 3; ++j)
            C[i * 3 + j] = A[i * 3 + 0] * B[0 * 3 + j] + A[i * 3 + 1] * B[1 * 3 + j] + A[i * 3 + 2] * B[2 * 3 + j];
}
static __device__ __forceinline__ void mv3(const float* A, const float* x, float* y) {
#pragma unroll
    for (int i = 0; i < 3; ++i) y[i] = A[i * 3 + 0] * x[0] + A[i * 3 + 1] * x[1] + A[i * 3 + 2] * x[2];
}
static __device__ __forceinline__ void mtv3(const float* A, const float* x, float* y) {
#pragma unroll
    for (int i = 0; i < 3; ++i) y[i] = A[0 * 3 + i] * x[0] + A[1 * 3 + i] * x[1] + A[2 * 3 + i] * x[2];
}
static __device__ __forceinline__ void cross3(const float* p, const float* u, float* y) {
    y[0] = p[1] * u[2] - p[2] * u[1];
    y[1] = p[2] * u[0] - p[0] * u[2];
    y[2] = p[0] * u[1] - p[1] * u[0];
}

// ws layout (unsigned short elements) — verified r6/r7/r9/r10:
//  [0,4096)      W1A: [n1=128][k=32] bf16, k>=12 zero
//  [4096,20480)  W2B: [n2=128][k=128] bf16
//  [20480,22528) W3B: [(kt*4+lg)*16 + n3pad]*8, n3pad<6 valid else 0
__global__ __launch_bounds__(256)
void weights_prep(const float* __restrict__ W1, const float* __restrict__ W2,
                  const float* __restrict__ W3, unsigned short* __restrict__ ws) {
    int i = blockIdx.x * 256 + threadIdx.x;
    if (i < 4096) {
        int n = i >> 5, k = i & 31;
        ws[i] = (k < 12) ? (unsigned short)bf16rne(W1[n * 12 + k]) : (unsigned short)0;
    } else if (i < 20480) {
        ws[i] = (unsigned short)bf16rne(W2[i - 4096]);
    } else if (i < 22528) {
        int j = i - 20480;
        int jj = j & 7;
        int l = (j >> 3) & 15;     // n3 (valid < 6)
        int kl = j >> 7;           // kt*4+lg
        int k = kl * 8 + jj;
        ws[i] = (l < 6) ? (unsigned short)bf16rne(W3[l * 128 + k]) : (unsigned short)0;
    }
}

// r10 envelope (1-wave blocks, T14 preloads, SE3 overlap, xv reuse) with the
// r7 REGULAR-DS data path: XOR-swizzled l12, ds_read_b128 A-frags, scalar b16
// C-stores. ZERO inline-asm LDS ops -> the compiler inserts precise counted
// lgkmcnt waits and pipelines reads into MFMAs (m97 behavior); no manual
// drains needed (r11 race was tr-asm-specific). Conflicts drop 4.2M -> ~0.3M.
// LDS: l12 [0,16384) + h1t [16384,18432) = 18432 B -> 8 blocks/CU.
__global__ __launch_bounds__(64, 3)
void auv_mfma10_kernel(const float* __restrict__ s, const float* __restrict__ a,
                       const float* __restrict__ h0, const float* __restrict__ W_ih,
                       const float* __restrict__ W_hh, const unsigned short* __restrict__ Wbf,
                       float* __restrict__ out, int K)
{
    __shared__ __align__(16) char lds[18432];
    const int lane = threadIdx.x & 63;
    const int l15  = lane & 15;
    const int lg   = lane >> 4;

    char* l12 = &lds[0];            // 64 rows x 256B, XOR swizzle ((row&15)<<4)
    char* h1t = &lds[16384];        // 64 rows x 32B
    char* dvt = &lds[0];            // overlay after af3 reads (compiler-ordered)

    const unsigned short* W1A = Wbf;
    const unsigned short* W2B = Wbf + 4096;
    const unsigned short* W3B = Wbf + 20480;

    const int e_raw = blockIdx.x * 64 + lane;
    const int e  = e_raw < K ? e_raw : K - 1;
    const bool live = e_raw < K;

    const float* srow = s  + (size_t)e * 18;
    const float* arow = a  + (size_t)e * 6;
    const float* hrow = h0 + (size_t)e * 12;

    // ---------------- Phase 1: RNN (scalar; W rows wave-uniform -> s_load) ----------------
    float pv3[3];
    pv3[0] = srow[0]; pv3[1] = srow[1]; pv3[2] = srow[2];
    float xv[21];
#pragma unroll
    for (int i = 0; i < 15; ++i) xv[i] = srow[3 + i];
#pragma unroll
    for (int i = 0; i < 6; ++i)  xv[15 + i] = arow[i];
    float h0v[12];
#pragma unroll
    for (int i = 0; i < 12; ++i) h0v[i] = hrow[i];

    float h1v[12];
#pragma unroll
    for (int j = 0; j < 12; ++j) {
        float acc = 0.f;
        const float* wih = W_ih + j * 21;
#pragma unroll
        for (int i = 0; i < 21; ++i) acc = fmaf(wih[i], xv[i], acc);
        const float* whh = W_hh + j * 12;
#pragma unroll
        for (int i = 0; i < 12; ++i) acc = fmaf(whh[i], h0v[i], acc);
        h1v[j] = tanh_fast(acc);
    }

    if (live) {
        float4* h4 = (float4*)(out + (size_t)K * 18 + (size_t)e * 12);
        h4[0] = make_float4(h1v[0], h1v[1], h1v[2], h1v[3]);
        h4[1] = make_float4(h1v[4], h1v[5], h1v[6], h1v[7]);
        h4[2] = make_float4(h1v[8], h1v[9], h1v[10], h1v[11]);
    }

    // T14: issue W2B nt=0 B-frag loads NOW (consumed in P4)
    short8 bfr[4];
#pragma unroll
    for (int kt = 0; kt < 4; ++kt)
        bfr[kt] = __builtin_bit_cast(short8,
            *(const uint4*)(W2B + (l15 * 128 + kt * 32 + lg * 8)));

    // h1 -> h1t: row=lane, 16 bf16 (12 valid + 4 zero); chunk swizzle by (row&1)
    {
        unsigned p0 = bf16pk2(h1v[0], h1v[1]);
        unsigned p1 = bf16pk2(h1v[2], h1v[3]);
        unsigned p2 = bf16pk2(h1v[4], h1v[5]);
        unsigned p3 = bf16pk2(h1v[6], h1v[7]);
        unsigned p4 = bf16pk2(h1v[8], h1v[9]);
        unsigned p5 = bf16pk2(h1v[10], h1v[11]);
        int rq = (lane & 1) << 4;
        *(uint4*)(h1t + lane * 32 + (0 ^ rq))  = make_uint4(p0, p1, p2, p3);
        *(uint4*)(h1t + lane * 32 + (16 ^ rq)) = make_uint4(p4, p5, 0u, 0u);
    }

    const short8 zfrag = {0, 0, 0, 0, 0, 0, 0, 0};

    // ---------------- Phase 2: Layer 1 via MFMA (K=32 zero-padded) ----------------
    short8 af1[4];
#pragma unroll
    for (int rt = 0; rt < 4; ++rt) {
        af1[rt] = zfrag;
        if (lg < 2) {
            int row = rt * 16 + l15;
            af1[rt] = __builtin_bit_cast(short8,
                *(const uint4*)(h1t + row * 32 + ((lg * 16) ^ ((row & 1) << 4))));
        }
    }
#pragma unroll 1
    for (int nt = 0; nt < 8; ++nt) {
        short8 b1 = __builtin_bit_cast(short8,
            *(const uint4*)(W1A + ((nt * 16 + l15) * 32 + lg * 8)));
#pragma unroll
        for (int rt = 0; rt < 4; ++rt) {
            f32x4 z = {0.f, 0.f, 0.f, 0.f};
            f32x4 c1 = __builtin_amdgcn_mfma_f32_16x16x32_bf16(af1[rt], b1, z, 0, 0, 0);
#pragma unroll
            for (int r = 0; r < 4; ++r) {
                int row = rt * 16 + lg * 4 + r;
                float v = c1[r];
                v = fmaxf(v, 0.1f * v);
                *(unsigned short*)(l12 + row * 256 +
                    (((nt * 16 + l15) * 2) ^ ((row & 15) << 4))) = bf16pk1(v);
            }
        }
    }

    // ---------------- Phase 3: A2 fragments (regular ds_read_b128) ----------------
    short8 af2[4][4];
#pragma unroll
    for (int rt = 0; rt < 4; ++rt)
#pragma unroll
        for (int kt = 0; kt < 4; ++kt) {
            int row = rt * 16 + l15;
            af2[rt][kt] = __builtin_bit_cast(short8,
                *(const uint4*)(l12 + row * 256 + ((kt * 64 + lg * 16) ^ ((row & 15) << 4))));
        }

    // T14: W3B loads issued early (consumed in P6)
    short8 b3f[4];
#pragma unroll
    for (int kt = 0; kt < 4; ++kt)
        b3f[kt] = __builtin_bit_cast(short8,
            *(const uint4*)(W3B + (((kt * 4 + lg) * 16 + l15) * 8)));

    // ---------------- Phase 4: Layer 2 via MFMA (bfr preloaded; bnext prefetch) ----------------
#pragma unroll 1
    for (int nt = 0; nt < 8; ++nt) {
        short8 bnext[4];
        if (nt < 7) {
#pragma unroll
            for (int kt = 0; kt < 4; ++kt)
                bnext[kt] = __builtin_bit_cast(short8,
                    *(const uint4*)(W2B + (((nt + 1) * 16 + l15) * 128 + kt * 32 + lg * 8)));
        }
#pragma unroll
        for (int rt = 0; rt < 4; ++rt) {
            f32x4 c2 = {0.f, 0.f, 0.f, 0.f};
#pragma unroll
            for (int kt = 0; kt < 4; ++kt)
                c2 = __builtin_amdgcn_mfma_f32_16x16x32_bf16(af2[rt][kt], bfr[kt], c2, 0, 0, 0);
#pragma unroll
            for (int r = 0; r < 4; ++r) {
                int row = rt * 16 + lg * 4 + r;
                float v = c2[r];
                v = fmaxf(v, 0.1f * v);
                *(unsigned short*)(l12 + row * 256 +
                    (((nt * 16 + l15) * 2) ^ ((row & 15) << 4))) = bf16pk1(v);
            }
        }
#pragma unroll
        for (int kt = 0; kt < 4; ++kt) bfr[kt] = bnext[kt];
    }

    // ---------------- Phase 5: A3 fragments (regular reads) + SE3 part 1 ----------------
    short8 af3[4][4];
#pragma unroll
    for (int rt = 0; rt < 4; ++rt)
#pragma unroll
        for (int kt = 0; kt < 4; ++kt) {
            int row = rt * 16 + l15;
            af3[rt][kt] = __builtin_bit_cast(short8,
                *(const uint4*)(l12 + row * 256 + ((kt * 64 + lg * 16) ^ ((row & 15) << 4))));
        }

    // dv-independent SE(3) work (R,v from xv; p from pv3 — no s re-read)
    const float* v = &xv[9];
    const float* p = pv3;
    const float* R = &xv[0];

    float Rn[9], pn[3], pinv[3], Rvl[3], Rva[3], px[3];
    {
        float rho[3] = {v[0] * DT_STEP, v[1] * DT_STEP, v[2] * DT_STEP};
        float phi[3] = {v[3] * DT_STEP, v[4] * DT_STEP, v[5] * DT_STEP};
        float th2 = phi[0] * phi[0] + phi[1] * phi[1] + phi[2] * phi[2];

        float A, B, C;
        if (th2 < 1e-8f) {
            A = 1.0f - th2 * (1.0f / 6.0f);
            B = 0.5f - th2 * (1.0f / 24.0f);
            C = (1.0f / 6.0f) - th2 * (1.0f / 120.0f);
        } else {
            float th = sqrtf(th2);
            float sn = sinf(th), cs = cosf(th);
            A = sn / th;
            B = (1.0f - cs) / th2;
            C = (th - sn) / (th2 * th);
        }

        float S[9] = {0.f, -phi[2], phi[1], phi[2], 0.f, -phi[0], -phi[1], phi[0], 0.f};
        float S2[9];
        mm3(S, S, S2);

        float Re[9], V[9];
#pragma unroll
        for (int i = 0; i < 9; ++i) {
            float I = (i == 0 || i == 4 || i == 8) ? 1.0f : 0.0f;
            Re[i] = I + A * S[i] + B * S2[i];
            V[i]  = I + B * S[i] + C * S2[i];
        }

        float pe[3];
        mv3(V, rho, pe);
        mm3(R, Re, Rn);
        mv3(R, pe, pn);
        pn[0] += p[0]; pn[1] += p[1]; pn[2] += p[2];

        mtv3(Rn, pn, pinv);
        pinv[0] = -pinv[0]; pinv[1] = -pinv[1]; pinv[2] = -pinv[2];

        mv3(R, &v[0], Rvl);
        mv3(R, &v[3], Rva);
        cross3(p, Rva, px);
    }

    // ---------------- Phase 6: Layer 3 via MFMA (n3 padded to 16) ----------------
    f32x4 c3[4];
#pragma unroll
    for (int rt = 0; rt < 4; ++rt) c3[rt] = (f32x4){0.f, 0.f, 0.f, 0.f};
#pragma unroll
    for (int kt = 0; kt < 4; ++kt) {
#pragma unroll
        for (int rt = 0; rt < 4; ++rt)
            c3[rt] = __builtin_amdgcn_mfma_f32_16x16x32_bf16(af3[rt][kt], b3f[kt], c3[rt], 0, 0, 0);
    }

    // ---------------- Phase 7: dv redistribute via dvt overlay (64 rows x 32B f32) ----------------
    // dvt aliases l12 rows 0..7 region: compiler orders af3 reads before these
    // writes (LDS aliasing), and the write->read below via memory deps.
    float dvv[6];
    if (l15 < 6) {
#pragma unroll
        for (int rt = 0; rt < 4; ++rt)
#pragma unroll
            for (int r = 0; r < 4; ++r) {
                int row = rt * 16 + lg * 4 + r;
                *(float*)(dvt + row * 32 + l15 * 4) = c3[rt][r];
            }
    }
    __builtin_amdgcn_s_barrier();   // single-wave block: cheap; guarantees LDS visibility
    {
        const float* dr = (const float*)(dvt + lane * 32);
        dvv[0] = dr[0]; dvv[1] = dr[1]; dvv[2] = dr[2];
        dvv[3] = dr[3]; dvv[4] = dr[4]; dvv[5] = dr[5];
    }

    // ---------------- Phase 8: SE(3) tail (dv-dependent) ----------------
    float u6[6];
    u6[0] = Rvl[0] + px[0] + dvv[0];
    u6[1] = Rvl[1] + px[1] + dvv[1];
    u6[2] = Rvl[2] + px[2] + dvv[2];
    u6[3] = Rva[0] + dvv[3];
    u6[4] = Rva[1] + dvv[4];
    u6[5] = Rva[2] + dvv[5];

    float Rul[3], Rua[3];
    mtv3(Rn, &u6[0], Rul);
    mtv3(Rn, &u6[3], Rua);
    float pxu[3];
    cross3(pinv, Rua, pxu);
    float vn[6];
    vn[0] = Rul[0] + pxu[0];
    vn[1] = Rul[1] + pxu[1];
    vn[2] = Rul[2] + pxu[2];
    vn[3] = Rua[0];
    vn[4] = Rua[1];
    vn[5] = Rua[2];

    if (live) {
        float* s_next = out + (size_t)e * 18;
        s_next[0] = pn[0]; s_next[1] = pn[1]; s_next[2] = pn[2];
#pragma unroll
        for (int i = 0; i < 9; ++i) s_next[3 + i] = Rn[i];
#pragma unroll
        for (int i = 0; i < 6; ++i) s_next[12 + i] = vn[i];

        float* dvo = out + (size_t)K * 30 + (size_t)e * 6;
#pragma unroll
        for (int r = 0; r < 6; ++r) dvo[r] = dvv[r];
    }
}

extern "C" void kernel_launch(void* const* d_in, const int* in_sizes, int n_in,
                              void* d_out, int out_size, void* d_ws, size_t ws_size,
                              hipStream_t stream) {
    const float* s    = (const float*)d_in[0];
    const float* a    = (const float*)d_in[1];
    const float* h0   = (const float*)d_in[2];
    const float* W_ih = (const float*)d_in[3];
    const float* W_hh = (const float*)d_in[4];
    const float* W1   = (const float*)d_in[5];
    const float* W2   = (const float*)d_in[6];
    const float* W3   = (const float*)d_in[7];

    int K = in_sizes[0] / 18;
    unsigned short* ws = (unsigned short*)d_ws;

    weights_prep<<<(22528 + 255) / 256, 256, 0, stream>>>(W1, W2, W3, ws);

    int grid = (K + 63) / 64;
    auv_mfma10_kernel<<<grid, 64, 0, stream>>>(s, a, h0, W_ih, W_hh, ws,
                                               (float*)d_out, K);
}